// Round 10
// baseline (405.876 us; speedup 1.0000x reference)
//
#include <hip/hip_runtime.h>
#include <hip/hip_bf16.h>
#include <hip/hip_fp8.h>

#define TT 200
#define UU 50
#define BB 8
#define DJ 1024   // D_JOINT
#define DE 512    // D_ENC / D_DEC
#define VV 1024
#define M_TOTAL (BB*TT*UU)   // 80000
#define MB 80                // M rows per block
#define WINV (1.0f/32.0f)    // undo W_fc fp8 pre-scale

typedef float f32x4 __attribute__((ext_vector_type(4)));
typedef long long2_t __attribute__((ext_vector_type(2)));

__device__ __forceinline__ float fast_tanh(float x) {
    float e = __expf(2.f * x);
    return 1.f - 2.f / (e + 1.f);
}

__device__ __forceinline__ unsigned char f2fp8(float x) {
    return __hip_fp8_e4m3(x).__x;   // OCP e4m3, satfinite
}

__device__ __forceinline__ unsigned long long tanh_pack_fp8(float4 e0, float4 e1, float4 d0, float4 d1) {
    unsigned long long r;
    r  = (unsigned long long)f2fp8(fast_tanh(e0.x + d0.x));
    r |= (unsigned long long)f2fp8(fast_tanh(e0.y + d0.y)) << 8;
    r |= (unsigned long long)f2fp8(fast_tanh(e0.z + d0.z)) << 16;
    r |= (unsigned long long)f2fp8(fast_tanh(e0.w + d0.w)) << 24;
    r |= (unsigned long long)f2fp8(fast_tanh(e1.x + d1.x)) << 32;
    r |= (unsigned long long)f2fp8(fast_tanh(e1.y + d1.y)) << 40;
    r |= (unsigned long long)f2fp8(fast_tanh(e1.z + d1.z)) << 48;
    r |= (unsigned long long)f2fp8(fast_tanh(e1.w + d1.w)) << 56;
    return r;
}

// ---------- kernel 1: W_fc fp32 [n][k] -> fp8 e4m3 (x32), K-PAIR-interleaved layout ----------
// granule gk=k/8: kb2=gk>>3 (64-K pair), sub=(gk>>2)&1 (which 32-chunk), g=gk&3 (k-slice)
// byte addr = kb2*65536 + n*64 + g*16 + sub*8  -> lane (g,ln) reads 16B covering both subs.
__global__ void k_wfct(const float* __restrict__ w, unsigned char* __restrict__ o) {
    const int G = blockIdx.x * 256 + threadIdx.x;   // 131072 granules
    const int gk = G >> 10, n = G & 1023;
    const float* src = w + (size_t)n * DJ + gk * 8;
    float4 a = *(const float4*)(src);
    float4 b = *(const float4*)(src + 4);
    unsigned long long r;
    r  = (unsigned long long)f2fp8(a.x * 32.f);
    r |= (unsigned long long)f2fp8(a.y * 32.f) << 8;
    r |= (unsigned long long)f2fp8(a.z * 32.f) << 16;
    r |= (unsigned long long)f2fp8(a.w * 32.f) << 24;
    r |= (unsigned long long)f2fp8(b.x * 32.f) << 32;
    r |= (unsigned long long)f2fp8(b.y * 32.f) << 40;
    r |= (unsigned long long)f2fp8(b.z * 32.f) << 48;
    r |= (unsigned long long)f2fp8(b.w * 32.f) << 56;
    const int kb2 = gk >> 3, sub = (gk >> 2) & 1, g = gk & 3;
    *(unsigned long long*)(o + (size_t)kb2 * 65536 + (size_t)n * 64 + g * 16 + sub * 8) = r;
}

// ---------- kernel 2: projections -> GRANULE-MAJOR f32 [gk][rows][8] ----------
__global__ __launch_bounds__(256) void k_proj2(const float* __restrict__ enc,
                                               const float* __restrict__ dec,
                                               const float* __restrict__ W_enc,
                                               const float* __restrict__ b_enc,
                                               const float* __restrict__ W_dec,
                                               const float* __restrict__ b_dec,
                                               float* __restrict__ encp,
                                               float* __restrict__ decp) {
    __shared__ float in_s[16][DE];
    const bool isDec = blockIdx.x >= 100;
    const float* in  = isDec ? dec   : enc;
    const float* W   = isDec ? W_dec : W_enc;
    const float* bia = isDec ? b_dec : b_enc;
    float* out       = isDec ? decp  : encp;
    const int NR     = isDec ? (BB*UU) : (BB*TT);
    const int m0 = (isDec ? (blockIdx.x - 100) : blockIdx.x) * 16;
    const int tid = threadIdx.x;
    #pragma unroll
    for (int it = 0; it < 8; ++it) {
        int idx = tid + it * 256;
        int r = idx >> 7, c = (idx & 127) << 2;
        *(float4*)&in_s[r][c] = *(const float4*)(in + (size_t)(m0 + r) * DE + c);
    }
    __syncthreads();
    const int j = blockIdx.y * 256 + tid;
    const float4* wr = (const float4*)(W + (size_t)j * DE);
    float acc[16];
    #pragma unroll
    for (int r = 0; r < 16; ++r) acc[r] = 0.f;
    for (int d4 = 0; d4 < DE / 4; ++d4) {
        float4 w = wr[d4];
        #pragma unroll
        for (int r = 0; r < 16; ++r) {
            float4 x = *(const float4*)&in_s[r][d4 << 2];
            acc[r] += x.x * w.x + x.y * w.y + x.z * w.z + x.w * w.w;
        }
    }
    float bv = bia[j];
    const int gk = j >> 3, kl = j & 7;
    #pragma unroll
    for (int r = 0; r < 16; ++r)
        out[((size_t)gk * NR + (m0 + r)) * 8 + kl] = acc[r] + bv;
}

// ---------- kernel 3: fused tanh(enc+dec) @ W_fc^T + b_fc -> log_softmax ----------
// 512 threads (8 waves), 80 M x 1024 N per block, fp8 GEMM, BARRIER-FREE main loop.
// A-stripe (80 KB, K-pair-interleaved) computed into LDS in prologue.
// Main loop over 16 K-pairs (64 K each): register double-buffer — issue next pair's
// 8x global dwordx4 (B) + 5x ds_read_b128 (A), then 80 MFMA on current pair.
__global__ __launch_bounds__(512, 2) void k_joint(const float* __restrict__ encp,
                                                  const float* __restrict__ decp,
                                                  const unsigned char* __restrict__ wfc8,
                                                  const float* __restrict__ bfc,
                                                  float* __restrict__ out) {
    __shared__ long2_t As4[5120];            // 80 KB: slot (kb2*4+g)*80 + m, halves = sub
    __shared__ float red[8][MB];             // 2.5 KB

    const int tid = threadIdx.x;
    const int wave = tid >> 6, lane = tid & 63;
    const int g = lane >> 4, ln = lane & 15;
    const int bid = blockIdx.x;
    const int m0 = bid * MB;

    // ---- prologue: compute A-stripe (tanh -> fp8) into LDS, pair-interleaved ----
    for (int r = 0; r < 20; ++r) {
        const int gidx = r * 512 + tid;          // gkf*80 + m, 10240 granules
        const int gkf = gidx / MB;
        const int m = gidx - gkf * MB;
        const int mrow = m0 + m;
        const int b = mrow / (TT * UU);
        const int rem = mrow - b * (TT * UU);
        const int t = rem / UU;
        const int u = rem - t * UU;
        const float* ep = encp + ((size_t)gkf * (BB * TT) + b * TT + t) * 8;
        const float* dp = decp + ((size_t)gkf * (BB * UU) + b * UU + u) * 8;
        float4 e0 = *(const float4*)(ep);
        float4 e1 = *(const float4*)(ep + 4);
        float4 d0 = *(const float4*)(dp);
        float4 d1 = *(const float4*)(dp + 4);
        const int akb2 = gkf >> 3, asub = (gkf >> 2) & 1, ag = gkf & 3;
        ((unsigned long long*)&As4[(akb2 * 4 + ag) * 80 + m])[asub] = tanh_pack_fp8(e0, e1, d0, d1);
    }

    f32x4 acc[5][8];
    #pragma unroll
    for (int mf = 0; mf < 5; ++mf)
        #pragma unroll
        for (int nf = 0; nf < 8; ++nf)
            acc[mf][nf] = (f32x4){0.f, 0.f, 0.f, 0.f};

    __syncthreads();   // As ready; the ONLY main-path barrier

    // per-lane bases
    const unsigned char* bptr = wfc8 + wave * 8192 + ln * 64 + g * 16;   // + kb2*65536 + nf*1024
    const long2_t* aptr = As4 + g * 80 + ln;                             // + kb2*320 + mf*16

    long2_t bA[8], bB[8], aA[5], aB[5];
    {
        const int k0 = bid & 15;
        #pragma unroll
        for (int nf = 0; nf < 8; ++nf)
            bA[nf] = *(const long2_t*)(bptr + (size_t)k0 * 65536 + nf * 1024);
        #pragma unroll
        for (int mf = 0; mf < 5; ++mf)
            aA[mf] = aptr[k0 * 320 + mf * 16];
    }

#define STEP(CA, CB, NA, NB, T2)                                                          \
    do {                                                                                  \
        if ((T2) < 15) {                                                                  \
            const int kn = ((T2) + 1 + bid) & 15;                                         \
            _Pragma("unroll")                                                             \
            for (int nf = 0; nf < 8; ++nf)                                                \
                NB[nf] = *(const long2_t*)(bptr + (size_t)kn * 65536 + nf * 1024);        \
            _Pragma("unroll")                                                             \
            for (int mf = 0; mf < 5; ++mf)                                                \
                NA[mf] = aptr[kn * 320 + mf * 16];                                        \
        }                                                                                 \
        _Pragma("unroll")                                                                 \
        for (int nf = 0; nf < 8; ++nf)                                                    \
            _Pragma("unroll")                                                             \
            for (int s = 0; s < 2; ++s)                                                   \
                _Pragma("unroll")                                                         \
                for (int mf = 0; mf < 5; ++mf)                                            \
                    acc[mf][nf] = __builtin_amdgcn_mfma_f32_16x16x32_fp8_fp8(             \
                        CA[mf][s], CB[nf][s], acc[mf][nf], 0, 0, 0);                      \
    } while (0)

    for (int t2 = 0; t2 < 16; t2 += 2) {
        STEP(aA, bA, aB, bB, t2);
        STEP(aB, bB, aA, bA, t2 + 1);
    }
#undef STEP

    // ---- fused log_softmax epilogue ----
    // C frag (mf,nf): row = mf*16 + g*4 + j, col = wave*128 + nf*16 + ln
    float bv[8];
    #pragma unroll
    for (int nf = 0; nf < 8; ++nf) bv[nf] = bfc[wave * 128 + nf * 16 + ln];
    #pragma unroll
    for (int mf = 0; mf < 5; ++mf)
        #pragma unroll
        for (int nf = 0; nf < 8; ++nf)
            #pragma unroll
            for (int j = 0; j < 4; ++j)
                acc[mf][nf][j] = acc[mf][nf][j] * WINV + bv[nf];

    float rmx[5][4];
    #pragma unroll
    for (int mf = 0; mf < 5; ++mf)
        #pragma unroll
        for (int j = 0; j < 4; ++j) {
            float mx = -3.0e38f;
            #pragma unroll
            for (int nf = 0; nf < 8; ++nf) mx = fmaxf(mx, acc[mf][nf][j]);
            #pragma unroll
            for (int s = 1; s < 16; s <<= 1) mx = fmaxf(mx, __shfl_xor(mx, s));
            rmx[mf][j] = mx;
        }
    if (ln == 0) {
        #pragma unroll
        for (int mf = 0; mf < 5; ++mf)
            #pragma unroll
            for (int j = 0; j < 4; ++j)
                red[wave][mf * 16 + g * 4 + j] = rmx[mf][j];
    }
    __syncthreads();
    #pragma unroll
    for (int mf = 0; mf < 5; ++mf)
        #pragma unroll
        for (int j = 0; j < 4; ++j) {
            const int r = mf * 16 + g * 4 + j;
            float mx = red[0][r];
            #pragma unroll
            for (int w = 1; w < 8; ++w) mx = fmaxf(mx, red[w][r]);
            rmx[mf][j] = mx;
        }
    __syncthreads();   // red reused for sums

    float rsm[5][4];
    #pragma unroll
    for (int mf = 0; mf < 5; ++mf)
        #pragma unroll
        for (int j = 0; j < 4; ++j) {
            float s = 0.f;
            #pragma unroll
            for (int nf = 0; nf < 8; ++nf) s += __expf(acc[mf][nf][j] - rmx[mf][j]);
            #pragma unroll
            for (int t2 = 1; t2 < 16; t2 <<= 1) s += __shfl_xor(s, t2);
            rsm[mf][j] = s;
        }
    if (ln == 0) {
        #pragma unroll
        for (int mf = 0; mf < 5; ++mf)
            #pragma unroll
            for (int j = 0; j < 4; ++j)
                red[wave][mf * 16 + g * 4 + j] = rsm[mf][j];
    }
    __syncthreads();
    #pragma unroll
    for (int mf = 0; mf < 5; ++mf)
        #pragma unroll
        for (int j = 0; j < 4; ++j) {
            const int r = mf * 16 + g * 4 + j;
            float s = 0.f;
            #pragma unroll
            for (int w = 0; w < 8; ++w) s += red[w][r];
            const float lse = rmx[mf][j] + __logf(s);
            float* op = out + (size_t)(m0 + r) * VV + wave * 128 + ln;
            #pragma unroll
            for (int nf = 0; nf < 8; ++nf)
                __builtin_nontemporal_store(acc[mf][nf][j] - lse, op + nf * 16);
        }
}

extern "C" void kernel_launch(void* const* d_in, const int* in_sizes, int n_in,
                              void* d_out, int out_size, void* d_ws, size_t ws_size,
                              hipStream_t stream) {
    const float* enc   = (const float*)d_in[0];
    const float* dec   = (const float*)d_in[1];
    const float* W_enc = (const float*)d_in[2];
    const float* b_enc = (const float*)d_in[3];
    const float* W_dec = (const float*)d_in[4];
    const float* b_dec = (const float*)d_in[5];
    const float* W_fc  = (const float*)d_in[6];
    const float* b_fc  = (const float*)d_in[7];
    float* out = (float*)d_out;

    float* encp = (float*)d_ws;                               // 1600*1024 f32, granule-major
    float* decp = encp + (size_t)BB * TT * DJ;                //  400*1024 f32, granule-major
    unsigned char* wfc8 = (unsigned char*)(decp + (size_t)BB * UU * DJ);  // 1 MB fp8, pair-interleaved
    // total ws: 9.2 MB (same footprint as passing rounds)

    k_wfct<<<(VV * DJ) / (256 * 8), 256, 0, stream>>>(W_fc, wfc8);
    k_proj2<<<dim3(125, DJ / 256), 256, 0, stream>>>(enc, dec, W_enc, b_enc, W_dec, b_dec, encp, decp);
    k_joint<<<M_TOTAL / MB, 512, 0, stream>>>(encp, decp, wfc8, b_fc, out);
}

// Round 11
// 324.964 us; speedup vs baseline: 1.2490x; 1.2490x over previous
//
#include <hip/hip_runtime.h>
#include <hip/hip_bf16.h>
#include <hip/hip_fp8.h>

#define TT 200
#define UU 50
#define BB 8
#define DJ 1024   // D_JOINT
#define DE 512    // D_ENC / D_DEC
#define VV 1024
#define M_TOTAL (BB*TT*UU)   // 80000
#define MB 80                // M rows per block
#define NITER 32             // K / 32
#define WINV (1.0f/32.0f)    // undo W_fc fp8 pre-scale

typedef float f32x4 __attribute__((ext_vector_type(4)));

__device__ __forceinline__ float fast_tanh(float x) {
    float e = __expf(2.f * x);
    return 1.f - 2.f / (e + 1.f);
}

__device__ __forceinline__ unsigned char f2fp8(float x) {
    return __hip_fp8_e4m3(x).__x;   // OCP e4m3, satfinite
}

__device__ __forceinline__ unsigned long long tanh_pack_fp8(float4 e0, float4 e1, float4 d0, float4 d1) {
    unsigned long long r;
    r  = (unsigned long long)f2fp8(fast_tanh(e0.x + d0.x));
    r |= (unsigned long long)f2fp8(fast_tanh(e0.y + d0.y)) << 8;
    r |= (unsigned long long)f2fp8(fast_tanh(e0.z + d0.z)) << 16;
    r |= (unsigned long long)f2fp8(fast_tanh(e0.w + d0.w)) << 24;
    r |= (unsigned long long)f2fp8(fast_tanh(e1.x + d1.x)) << 32;
    r |= (unsigned long long)f2fp8(fast_tanh(e1.y + d1.y)) << 40;
    r |= (unsigned long long)f2fp8(fast_tanh(e1.z + d1.z)) << 48;
    r |= (unsigned long long)f2fp8(fast_tanh(e1.w + d1.w)) << 56;
    return r;
}

// ---------- kernel 1: W_fc fp32 [n][k] -> fp8 e4m3 (x32) granule-major [gk][n] ----------
__global__ void k_wfct(const float* __restrict__ w, unsigned char* __restrict__ o) {
    const int G = blockIdx.x * 256 + threadIdx.x;   // 131072 granules
    const int gk = G >> 10, n = G & 1023;
    const float* src = w + (size_t)n * DJ + gk * 8;
    float4 a = *(const float4*)(src);
    float4 b = *(const float4*)(src + 4);
    unsigned long long r;
    r  = (unsigned long long)f2fp8(a.x * 32.f);
    r |= (unsigned long long)f2fp8(a.y * 32.f) << 8;
    r |= (unsigned long long)f2fp8(a.z * 32.f) << 16;
    r |= (unsigned long long)f2fp8(a.w * 32.f) << 24;
    r |= (unsigned long long)f2fp8(b.x * 32.f) << 32;
    r |= (unsigned long long)f2fp8(b.y * 32.f) << 40;
    r |= (unsigned long long)f2fp8(b.z * 32.f) << 48;
    r |= (unsigned long long)f2fp8(b.w * 32.f) << 56;
    *(unsigned long long*)(o + (size_t)G * 8) = r;
}

// ---------- kernel 2: projections -> GRANULE-MAJOR f32 [gk][rows][8] ----------
__global__ __launch_bounds__(256) void k_proj2(const float* __restrict__ enc,
                                               const float* __restrict__ dec,
                                               const float* __restrict__ W_enc,
                                               const float* __restrict__ b_enc,
                                               const float* __restrict__ W_dec,
                                               const float* __restrict__ b_dec,
                                               float* __restrict__ encp,
                                               float* __restrict__ decp) {
    __shared__ float in_s[16][DE];
    const bool isDec = blockIdx.x >= 100;
    const float* in  = isDec ? dec   : enc;
    const float* W   = isDec ? W_dec : W_enc;
    const float* bia = isDec ? b_dec : b_enc;
    float* out       = isDec ? decp  : encp;
    const int NR     = isDec ? (BB*UU) : (BB*TT);
    const int m0 = (isDec ? (blockIdx.x - 100) : blockIdx.x) * 16;
    const int tid = threadIdx.x;
    #pragma unroll
    for (int it = 0; it < 8; ++it) {
        int idx = tid + it * 256;
        int r = idx >> 7, c = (idx & 127) << 2;
        *(float4*)&in_s[r][c] = *(const float4*)(in + (size_t)(m0 + r) * DE + c);
    }
    __syncthreads();
    const int j = blockIdx.y * 256 + tid;
    const float4* wr = (const float4*)(W + (size_t)j * DE);
    float acc[16];
    #pragma unroll
    for (int r = 0; r < 16; ++r) acc[r] = 0.f;
    for (int d4 = 0; d4 < DE / 4; ++d4) {
        float4 w = wr[d4];
        #pragma unroll
        for (int r = 0; r < 16; ++r) {
            float4 x = *(const float4*)&in_s[r][d4 << 2];
            acc[r] += x.x * w.x + x.y * w.y + x.z * w.z + x.w * w.w;
        }
    }
    float bv = bia[j];
    const int gk = j >> 3, kl = j & 7;
    #pragma unroll
    for (int r = 0; r < 16; ++r)
        out[((size_t)gk * NR + (m0 + r)) * 8 + kl] = acc[r] + bv;
}

// ---------- kernel 3: fused tanh(enc+dec) @ W_fc^T + b_fc -> log_softmax ----------
// 512 threads (8 waves), 80 M x 1024 N, fp8 GEMM, BARRIER-FREE main loop (round-9 base).
// NEW: register double-buffer of A/B fragments as plain 8B longs (+~46 VGPR, no spill):
// chunk t+1's 8 global longs + 5 LDS longs issue BEFORE the 40 MFMAs on chunk t,
// so their waitcnt lands ~790 cyc later instead of stalling the same iteration.
__global__ __launch_bounds__(512, 2) void k_joint(const float* __restrict__ encp,
                                                  const float* __restrict__ decp,
                                                  const unsigned char* __restrict__ wfc8,
                                                  const float* __restrict__ bfc,
                                                  float* __restrict__ out) {
    __shared__ unsigned char As[81920];      // 80 KB: granule (gkf 0..127, m 0..79)
    __shared__ float red[8][MB];             // 2.5 KB

    const int tid = threadIdx.x;
    const int wave = tid >> 6, lane = tid & 63;
    const int g = lane >> 4, ln = lane & 15;
    const int bid = blockIdx.x;
    const int m0 = bid * MB;

    // ---- prologue: compute A-stripe into LDS ----
    for (int r = 0; r < 20; ++r) {
        const int gidx = r * 512 + tid;          // 10240 granules: gkf*80 + m
        const int gkf = gidx / MB;
        const int m = gidx - gkf * MB;
        const int mrow = m0 + m;
        const int b = mrow / (TT * UU);
        const int rem = mrow - b * (TT * UU);
        const int t = rem / UU;
        const int u = rem - t * UU;
        const float* ep = encp + ((size_t)gkf * (BB * TT) + b * TT + t) * 8;
        const float* dp = decp + ((size_t)gkf * (BB * UU) + b * UU + u) * 8;
        float4 e0 = *(const float4*)(ep);
        float4 e1 = *(const float4*)(ep + 4);
        float4 d0 = *(const float4*)(dp);
        float4 d1 = *(const float4*)(dp + 4);
        *(unsigned long long*)&As[(size_t)gidx * 8] = tanh_pack_fp8(e0, e1, d0, d1);
    }

    f32x4 acc[5][8];
    #pragma unroll
    for (int mf = 0; mf < 5; ++mf)
        #pragma unroll
        for (int nf = 0; nf < 8; ++nf)
            acc[mf][nf] = (f32x4){0.f, 0.f, 0.f, 0.f};

    __syncthreads();   // As ready; the ONLY main-path barrier

    // per-wave B base: granule (gk, n) at wfc8 + (gk*1024 + n)*8
    const unsigned char* bbase = wfc8 + (size_t)(wave * 128 + ln) * 8;

    long bcur[8], bnxt[8], acur[5], anxt[5];
    {
        const int k0 = bid & 31;
        #pragma unroll
        for (int nf = 0; nf < 8; ++nf)
            bcur[nf] = *(const long*)(bbase + ((size_t)(k0 * 4 + g) * 1024 + nf * 16) * 8);
        #pragma unroll
        for (int mf = 0; mf < 5; ++mf)
            acur[mf] = *(const long*)&As[(size_t)((k0 * 4 + g) * MB + mf * 16 + ln) * 8];
    }

#define STEP(CA, CB, NA, NB, T)                                                           \
    do {                                                                                  \
        if ((T) < NITER - 1) {                                                            \
            const int kn = ((T) + 1 + bid) & 31;                                          \
            _Pragma("unroll")                                                             \
            for (int nf = 0; nf < 8; ++nf)                                                \
                NB[nf] = *(const long*)(bbase + ((size_t)(kn * 4 + g) * 1024 + nf * 16) * 8); \
            _Pragma("unroll")                                                             \
            for (int mf = 0; mf < 5; ++mf)                                                \
                NA[mf] = *(const long*)&As[(size_t)((kn * 4 + g) * MB + mf * 16 + ln) * 8];   \
        }                                                                                 \
        _Pragma("unroll")                                                                 \
        for (int nf = 0; nf < 8; ++nf)                                                    \
            _Pragma("unroll")                                                             \
            for (int mf = 0; mf < 5; ++mf)                                                \
                acc[mf][nf] = __builtin_amdgcn_mfma_f32_16x16x32_fp8_fp8(                 \
                    CA[mf], CB[nf], acc[mf][nf], 0, 0, 0);                                \
    } while (0)

    for (int t = 0; t < NITER; t += 2) {
        STEP(acur, bcur, anxt, bnxt, t);
        STEP(anxt, bnxt, acur, bcur, t + 1);
    }
#undef STEP

    // ---- fused log_softmax epilogue ----
    // C frag (mf,nf): row = mf*16 + g*4 + j, col = wave*128 + nf*16 + ln
    float bv[8];
    #pragma unroll
    for (int nf = 0; nf < 8; ++nf) bv[nf] = bfc[wave * 128 + nf * 16 + ln];
    #pragma unroll
    for (int mf = 0; mf < 5; ++mf)
        #pragma unroll
        for (int nf = 0; nf < 8; ++nf)
            #pragma unroll
            for (int j = 0; j < 4; ++j)
                acc[mf][nf][j] = acc[mf][nf][j] * WINV + bv[nf];

    float rmx[5][4];
    #pragma unroll
    for (int mf = 0; mf < 5; ++mf)
        #pragma unroll
        for (int j = 0; j < 4; ++j) {
            float mx = -3.0e38f;
            #pragma unroll
            for (int nf = 0; nf < 8; ++nf) mx = fmaxf(mx, acc[mf][nf][j]);
            #pragma unroll
            for (int s = 1; s < 16; s <<= 1) mx = fmaxf(mx, __shfl_xor(mx, s));
            rmx[mf][j] = mx;
        }
    if (ln == 0) {
        #pragma unroll
        for (int mf = 0; mf < 5; ++mf)
            #pragma unroll
            for (int j = 0; j < 4; ++j)
                red[wave][mf * 16 + g * 4 + j] = rmx[mf][j];
    }
    __syncthreads();
    #pragma unroll
    for (int mf = 0; mf < 5; ++mf)
        #pragma unroll
        for (int j = 0; j < 4; ++j) {
            const int r = mf * 16 + g * 4 + j;
            float mx = red[0][r];
            #pragma unroll
            for (int w = 1; w < 8; ++w) mx = fmaxf(mx, red[w][r]);
            rmx[mf][j] = mx;
        }
    __syncthreads();   // red reused for sums

    float rsm[5][4];
    #pragma unroll
    for (int mf = 0; mf < 5; ++mf)
        #pragma unroll
        for (int j = 0; j < 4; ++j) {
            float s = 0.f;
            #pragma unroll
            for (int nf = 0; nf < 8; ++nf) s += __expf(acc[mf][nf][j] - rmx[mf][j]);
            #pragma unroll
            for (int t2 = 1; t2 < 16; t2 <<= 1) s += __shfl_xor(s, t2);
            rsm[mf][j] = s;
        }
    if (ln == 0) {
        #pragma unroll
        for (int mf = 0; mf < 5; ++mf)
            #pragma unroll
            for (int j = 0; j < 4; ++j)
                red[wave][mf * 16 + g * 4 + j] = rsm[mf][j];
    }
    __syncthreads();
    #pragma unroll
    for (int mf = 0; mf < 5; ++mf)
        #pragma unroll
        for (int j = 0; j < 4; ++j) {
            const int r = mf * 16 + g * 4 + j;
            float s = 0.f;
            #pragma unroll
            for (int w = 0; w < 8; ++w) s += red[w][r];
            const float lse = rmx[mf][j] + __logf(s);
            float* op = out + (size_t)(m0 + r) * VV + wave * 128 + ln;
            #pragma unroll
            for (int nf = 0; nf < 8; ++nf)
                __builtin_nontemporal_store(acc[mf][nf][j] - lse, op + nf * 16);
        }
}

extern "C" void kernel_launch(void* const* d_in, const int* in_sizes, int n_in,
                              void* d_out, int out_size, void* d_ws, size_t ws_size,
                              hipStream_t stream) {
    const float* enc   = (const float*)d_in[0];
    const float* dec   = (const float*)d_in[1];
    const float* W_enc = (const float*)d_in[2];
    const float* b_enc = (const float*)d_in[3];
    const float* W_dec = (const float*)d_in[4];
    const float* b_dec = (const float*)d_in[5];
    const float* W_fc  = (const float*)d_in[6];
    const float* b_fc  = (const float*)d_in[7];
    float* out = (float*)d_out;

    float* encp = (float*)d_ws;                               // 1600*1024 f32, granule-major
    float* decp = encp + (size_t)BB * TT * DJ;                //  400*1024 f32, granule-major
    unsigned char* wfc8 = (unsigned char*)(decp + (size_t)BB * UU * DJ);  // 1 MB fp8, granule-major
    // total ws: 9.2 MB (same footprint as passing rounds)

    k_wfct<<<(VV * DJ) / (256 * 8), 256, 0, stream>>>(W_fc, wfc8);
    k_proj2<<<dim3(125, DJ / 256), 256, 0, stream>>>(enc, dec, W_enc, b_enc, W_dec, b_dec, encp, decp);
    k_joint<<<M_TOTAL / MB, 512, 0, stream>>>(encp, decp, wfc8, b_fc, out);
}